// Round 1
// baseline (94.545 us; speedup 1.0000x reference)
//
#include <hip/hip_runtime.h>

// Problem constants (from reference): G=14, B=64, T=2048, H=6
#define Gc 14
#define Hc 6
#define NPc (64*2048)      // B*T = 131072 independent points
#define LOG_2PI 1.8378770664093453f

__device__ __forceinline__ float safercp(float d) {
    // _dnn(x, d) = (d==0) ? 0 : x/d  -> multiply x by safercp(d)
    return (d == 0.0f) ? 0.0f : 1.0f / d;
}

// One _gaussian_product step, in-place on slot pair.
// c1,c2 are the "first pair" (scalars C1,C2 come from their k-th channel),
// n1,n2 the second pair, b1,b2 biases. Mirrors the reference op-for-op,
// with shared divisors hoisted into correctly-rounded reciprocals.
__device__ __forceinline__ void gprod(float (&c1)[Hc], float (&c2)[Hc],
                                      float (&n1)[Hc], float (&n2)[Hc],
                                      float &b1, float &b2, const int k,
                                      float &LC)
{
    const float C1 = c1[k];
    const float C2 = c2[k];
    const float r1 = safercp(C1);
    const float r2 = safercp(C2);
    const float var1 = r1 * r1;            // ref: 1/C1^2
    const float var2 = r2 * r2;            // ref: 1/C2^2
    const float var3 = var1 + var2;
    const float std3 = sqrtf(var3);
    const float rstd3 = 1.0f / std3;
    const float var4 = (var1 * var2) / var3;
    const float std4 = sqrtf(var4);
    const float den = var3 * std4;
    const float rden = 1.0f / den;

    // bias channel
    {
        const float bb1 = b1 * r1, bb2 = b2 * r2;
        b1 = (bb1 - bb2) * rstd3;
        b2 = (bb1 * var2 + bb2 * var1) * rden;
    }
    // 6 hidden channels (static indices after full unroll)
#pragma unroll
    for (int h = 0; h < Hc; ++h) {
        const float cc1 = c1[h] * r1, cc2 = c2[h] * r2;
        const float nn1 = n1[h] * r1, nn2 = n2[h] * r2;
        c1[h] = (cc1 - cc2) * rstd3;
        c2[h] = (cc1 * var2 + cc2 * var1) * rden;
        n1[h] = (nn1 - nn2) * rstd3;
        n2[h] = (nn1 * var2 + nn2 * var1) * rden;
    }
    LC -= logf(fabsf(C1 * C2 * std4 * std3));
}

__global__ void __launch_bounds__(256)
gaussmerge_kernel(const float* __restrict__ cur_in,
                  const float* __restrict__ nxt_in,
                  const float* __restrict__ b_in,
                  float* __restrict__ out)
{
    const int p = blockIdx.x * 256 + threadIdx.x;   // grid sized exactly NPc

    float cur[Gc][Hc];
    float nxt[Gc][Hc];
    float bb[Gc];

    // ---- load: per g, 6 contiguous floats at [g][p][*] (24B/lane, coalesced) ----
#pragma unroll
    for (int g = 0; g < Gc; ++g) {
        const float2* cs = reinterpret_cast<const float2*>(cur_in + (size_t)g * NPc * Hc + (size_t)p * Hc);
        const float2* ns = reinterpret_cast<const float2*>(nxt_in + (size_t)g * NPc * Hc + (size_t)p * Hc);
        float2 a0 = cs[0], a1 = cs[1], a2 = cs[2];
        cur[g][0] = a0.x; cur[g][1] = a0.y;
        cur[g][2] = a1.x; cur[g][3] = a1.y;
        cur[g][4] = a2.x; cur[g][5] = a2.y;
        float2 d0 = ns[0], d1 = ns[1], d2 = ns[2];
        nxt[g][0] = d0.x; nxt[g][1] = d0.y;
        nxt[g][2] = d1.x; nxt[g][3] = d1.y;
        nxt[g][4] = d2.x; nxt[g][5] = d2.y;
        bb[g] = b_in[(size_t)g * NPc + p];
    }

    float LC = 0.0f;

    // ---- phase 1: k = 0..5, list length n = 14-k, pair-sweep then drop last ----
#pragma unroll
    for (int k = 0; k < Hc; ++k) {
        const int n = Gc - k;
#pragma unroll
        for (int i = 0; i < n - 1; ++i)
            gprod(cur[i], cur[i + 1], nxt[i], nxt[i + 1], bb[i], bb[i + 1], k, LC);
        LC -= logf(fabsf(cur[n - 1][k]));
        // pop(n-1): implicit, later iterations only touch slots < n-1
    }

    // ---- phase 2: k = 0..5, length n = 8-k, roles of cur/nxt swapped ----
    float* outN = out;                                   // (6, B, T, H)
    float* outB = out + (size_t)Hc * NPc * Hc;           // (6, B, T)
    float* outL = outB + (size_t)Hc * NPc;               // (B, T)
#pragma unroll
    for (int k = 0; k < Hc; ++k) {
        const int n = (Gc - Hc) - k;   // 8 - k
#pragma unroll
        for (int i = 0; i < n - 1; ++i)
            gprod(nxt[i], nxt[i + 1], cur[i], cur[i + 1], bb[i], bb[i + 1], k, LC);
        // kept_n[k] = nxt[n-1], kept_b[k] = bb[n-1]
        float2* od = reinterpret_cast<float2*>(outN + (size_t)k * NPc * Hc + (size_t)p * Hc);
        od[0] = make_float2(nxt[n - 1][0], nxt[n - 1][1]);
        od[1] = make_float2(nxt[n - 1][2], nxt[n - 1][3]);
        od[2] = make_float2(nxt[n - 1][4], nxt[n - 1][5]);
        outB[(size_t)k * NPc + p] = bb[n - 1];
    }

    // ---- epilogue: remaining biases (slots 0,1) ----
    LC += -0.5f * (LOG_2PI + bb[0] * bb[0]);
    LC += -0.5f * (LOG_2PI + bb[1] * bb[1]);
    outL[p] = LC;
}

extern "C" void kernel_launch(void* const* d_in, const int* in_sizes, int n_in,
                              void* d_out, int out_size, void* d_ws, size_t ws_size,
                              hipStream_t stream) {
    const float* cur = (const float*)d_in[0];
    const float* nxt = (const float*)d_in[1];
    const float* bia = (const float*)d_in[2];
    float* out = (float*)d_out;

    dim3 grid(NPc / 256), block(256);
    gaussmerge_kernel<<<grid, block, 0, stream>>>(cur, nxt, bia, out);
}

// Round 2
// 44.854 us; speedup vs baseline: 2.1079x; 2.1079x over previous
//
#include <hip/hip_runtime.h>

// Problem constants (from reference): G=14, B=64, T=2048, H=6
#define Gc 14
#define Hc 6
#define NPc (64*2048)      // B*T = 131072 independent points
#define LOG_2PI 1.8378770664093453f

// v_rcp_f32 + 1 Newton step (~0.5 ulp), avoids the IEEE div expansion chain
__device__ __forceinline__ float fast_rcp(float x) {
    float r = __builtin_amdgcn_rcpf(x);
    return r * (2.0f - x * r);
}
// v_rsq_f32 + 1 Newton step
__device__ __forceinline__ float fast_rsq(float x) {
    float r = __builtin_amdgcn_rsqf(x);
    return r * (1.5f - 0.5f * x * r * r);
}

// One _gaussian_product step, in-place on slot pair.
// Algebraic identities used (exact math):
//   std3*std4 = sqrt(var1*var2) = 1/(|C1||C2|)  =>  logC = -log(1) = 0 (dropped)
//   1/std3    = rsqrt(var3)
//   1/den     = 1/(var3*std4) = rsqrt(var3)*|C1*C2|
//   at h==k:  c3[k] = 0 exactly, c4[k] = var3/den = 1/std4
__device__ __forceinline__ void gprod(float (&c1)[Hc], float (&c2)[Hc],
                                      float (&n1)[Hc], float (&n2)[Hc],
                                      float &b1, float &b2, const int k)
{
    const float C1 = c1[k], C2 = c2[k];
    const float r1 = (C1 == 0.0f) ? 0.0f : fast_rcp(C1);
    const float r2 = (C2 == 0.0f) ? 0.0f : fast_rcp(C2);
    const float var1 = r1 * r1;
    const float var2 = r2 * r2;
    const float var3 = var1 + var2;
    const float irs  = fast_rsq(var3);           // 1/std3
    const float rden = irs * fabsf(C1 * C2);     // 1/(var3*std4)

    // bias channel
    {
        const float bb1 = b1 * r1, bb2 = b2 * r2;
        b1 = (bb1 - bb2) * irs;
        b2 = fmaf(bb1, var2, bb2 * var1) * rden;
    }
    // 6 hidden channels; k is a compile-time constant after full unroll,
    // so the h==k branch resolves statically.
#pragma unroll
    for (int h = 0; h < Hc; ++h) {
        const float nn1 = n1[h] * r1, nn2 = n2[h] * r2;
        n1[h] = (nn1 - nn2) * irs;
        n2[h] = fmaf(nn1, var2, nn2 * var1) * rden;
        if (h == k) {
            c1[h] = 0.0f;                        // (1 - 1)/std3 exactly
            c2[h] = var3 * rden;                 // 1/std4
        } else {
            const float cc1 = c1[h] * r1, cc2 = c2[h] * r2;
            c1[h] = (cc1 - cc2) * irs;
            c2[h] = fmaf(cc1, var2, cc2 * var1) * rden;
        }
    }
}

__global__ void __launch_bounds__(256)
gaussmerge_kernel(const float* __restrict__ cur_in,
                  const float* __restrict__ nxt_in,
                  const float* __restrict__ b_in,
                  float* __restrict__ out)
{
    const int p = blockIdx.x * 256 + threadIdx.x;   // grid sized exactly NPc

    float cur[Gc][Hc];
    float nxt[Gc][Hc];
    float bb[Gc];

    // ---- load: per g, 6 contiguous floats at [g][p][*] (24B/lane) ----
#pragma unroll
    for (int g = 0; g < Gc; ++g) {
        const float2* cs = reinterpret_cast<const float2*>(cur_in + (size_t)g * NPc * Hc + (size_t)p * Hc);
        const float2* ns = reinterpret_cast<const float2*>(nxt_in + (size_t)g * NPc * Hc + (size_t)p * Hc);
        float2 a0 = cs[0], a1 = cs[1], a2 = cs[2];
        cur[g][0] = a0.x; cur[g][1] = a0.y;
        cur[g][2] = a1.x; cur[g][3] = a1.y;
        cur[g][4] = a2.x; cur[g][5] = a2.y;
        float2 d0 = ns[0], d1 = ns[1], d2 = ns[2];
        nxt[g][0] = d0.x; nxt[g][1] = d0.y;
        nxt[g][2] = d1.x; nxt[g][3] = d1.y;
        nxt[g][4] = d2.x; nxt[g][5] = d2.y;
        bb[g] = b_in[(size_t)g * NPc + p];
    }

    float LC = 0.0f;

    // ---- phase 1: k = 0..5, list length n = 14-k, pair-sweep then drop last ----
#pragma unroll
    for (int k = 0; k < Hc; ++k) {
        const int n = Gc - k;
#pragma unroll
        for (int i = 0; i < n - 1; ++i)
            gprod(cur[i], cur[i + 1], nxt[i], nxt[i + 1], bb[i], bb[i + 1], k);
        LC -= __logf(fabsf(cur[n - 1][k]));
        // pop(n-1): implicit, later iterations only touch slots < n-1
    }

    // ---- phase 2: k = 0..5, length n = 8-k, roles of cur/nxt swapped ----
    float* outN = out;                                   // (6, B, T, H)
    float* outB = out + (size_t)Hc * NPc * Hc;           // (6, B, T)
    float* outL = outB + (size_t)Hc * NPc;               // (B, T)
#pragma unroll
    for (int k = 0; k < Hc; ++k) {
        const int n = (Gc - Hc) - k;   // 8 - k
#pragma unroll
        for (int i = 0; i < n - 1; ++i)
            gprod(nxt[i], nxt[i + 1], cur[i], cur[i + 1], bb[i], bb[i + 1], k);
        // kept_n[k] = nxt[n-1], kept_b[k] = bb[n-1]
        float2* od = reinterpret_cast<float2*>(outN + (size_t)k * NPc * Hc + (size_t)p * Hc);
        od[0] = make_float2(nxt[n - 1][0], nxt[n - 1][1]);
        od[1] = make_float2(nxt[n - 1][2], nxt[n - 1][3]);
        od[2] = make_float2(nxt[n - 1][4], nxt[n - 1][5]);
        outB[(size_t)k * NPc + p] = bb[n - 1];
    }

    // ---- epilogue: remaining biases (slots 0,1) ----
    LC += -0.5f * (LOG_2PI + bb[0] * bb[0]);
    LC += -0.5f * (LOG_2PI + bb[1] * bb[1]);
    outL[p] = LC;
}

extern "C" void kernel_launch(void* const* d_in, const int* in_sizes, int n_in,
                              void* d_out, int out_size, void* d_ws, size_t ws_size,
                              hipStream_t stream) {
    const float* cur = (const float*)d_in[0];
    const float* nxt = (const float*)d_in[1];
    const float* bia = (const float*)d_in[2];
    float* out = (float*)d_out;

    dim3 grid(NPc / 256), block(256);
    gaussmerge_kernel<<<grid, block, 0, stream>>>(cur, nxt, bia, out);
}

// Round 3
// 41.948 us; speedup vs baseline: 2.2539x; 1.0693x over previous
//
#include <hip/hip_runtime.h>

// Problem constants (from reference): G=14, B=64, T=2048, H=6
#define Gc 14
#define Hc 6
#define NPc (64*2048)      // B*T = 131072 independent points
#define LOG_2PI 1.8378770664093453f

// Raw HW transcendentals (~1 ulp on gfx950), no Newton refinement.
__device__ __forceinline__ float fast_rcp(float x) { return __builtin_amdgcn_rcpf(x); }
__device__ __forceinline__ float fast_rsq(float x) { return __builtin_amdgcn_rsqf(x); }

// One _gaussian_product step, in-place on slot pair.
// Algebraic identities (exact math, using r*|C| == 1):
//   std3*std4 = 1/(|C1||C2|)            =>  logC = 0 (dropped)
//   x3 = (x1/C1 - x2/C2)/std3           =  x1*(r1*irs) - x2*(r2*irs)
//   x4 = (x1/C1*var2 + x2/C2*var1)/den  =  sgn(C1C2)*(x1*r2 + x2*r1)*irs
//   at h==k: c3[k] = 0 exactly, c4[k] = var3*irs*|C1C2|  (= 1/std4)
// => every channel update is 2 mul + 2 fma.
__device__ __forceinline__ void gprod(float (&c1)[Hc], float (&c2)[Hc],
                                      float (&n1)[Hc], float (&n2)[Hc],
                                      float &b1, float &b2, const int k)
{
    const float C1 = c1[k], C2 = c2[k];
    const float r1 = (C1 == 0.0f) ? 0.0f : fast_rcp(C1);
    const float r2 = (C2 == 0.0f) ? 0.0f : fast_rcp(C2);
    const float var3 = fmaf(r1, r1, r2 * r2);
    const float irs  = fast_rsq(var3);           // 1/std3
    const float pp   = C1 * C2;
    const float si   = copysignf(irs, pp);       // sgn(C1C2)/std3
    const float a1 = r1 * irs, a2 = r2 * irs;
    const float s1 = r1 * si,  s2 = r2 * si;

    // bias channel
    {
        const float t = b2 * a2, u = b2 * s1;
        const float nb1 = fmaf(b1, a1, -t);
        b2 = fmaf(b1, s2, u);
        b1 = nb1;
    }
    // 6 hidden channels; k is compile-time constant after full unroll.
#pragma unroll
    for (int h = 0; h < Hc; ++h) {
        {
            const float t = n2[h] * a2, u = n2[h] * s1;
            const float nn1 = fmaf(n1[h], a1, -t);
            n2[h] = fmaf(n1[h], s2, u);
            n1[h] = nn1;
        }
        if (h == k) {
            c1[h] = 0.0f;                          // exact, mirrors reference
            c2[h] = (var3 * irs) * fabsf(pp);      // 1/std4
        } else {
            const float t = c2[h] * a2, u = c2[h] * s1;
            const float nc1 = fmaf(c1[h], a1, -t);
            c2[h] = fmaf(c1[h], s2, u);
            c1[h] = nc1;
        }
    }
}

__global__ void __launch_bounds__(256)
gaussmerge_kernel(const float* __restrict__ cur_in,
                  const float* __restrict__ nxt_in,
                  const float* __restrict__ b_in,
                  float* __restrict__ out)
{
    const int p = blockIdx.x * 256 + threadIdx.x;   // grid sized exactly NPc

    float cur[Gc][Hc];
    float nxt[Gc][Hc];
    float bb[Gc];

    // ---- load: per g, 6 contiguous floats at [g][p][*] (24B/lane) ----
#pragma unroll
    for (int g = 0; g < Gc; ++g) {
        const float2* cs = reinterpret_cast<const float2*>(cur_in + (size_t)g * NPc * Hc + (size_t)p * Hc);
        const float2* ns = reinterpret_cast<const float2*>(nxt_in + (size_t)g * NPc * Hc + (size_t)p * Hc);
        float2 a0 = cs[0], a1 = cs[1], a2 = cs[2];
        cur[g][0] = a0.x; cur[g][1] = a0.y;
        cur[g][2] = a1.x; cur[g][3] = a1.y;
        cur[g][4] = a2.x; cur[g][5] = a2.y;
        float2 d0 = ns[0], d1 = ns[1], d2 = ns[2];
        nxt[g][0] = d0.x; nxt[g][1] = d0.y;
        nxt[g][2] = d1.x; nxt[g][3] = d1.y;
        nxt[g][4] = d2.x; nxt[g][5] = d2.y;
        bb[g] = b_in[(size_t)g * NPc + p];
    }

    float LC = 0.0f;

    // ---- phase 1: k = 0..5, list length n = 14-k, pair-sweep then drop last ----
#pragma unroll
    for (int k = 0; k < Hc; ++k) {
        const int n = Gc - k;
#pragma unroll
        for (int i = 0; i < n - 1; ++i)
            gprod(cur[i], cur[i + 1], nxt[i], nxt[i + 1], bb[i], bb[i + 1], k);
        LC -= __logf(fabsf(cur[n - 1][k]));
        // pop(n-1): implicit, later iterations only touch slots < n-1
    }

    // ---- phase 2: k = 0..5, length n = 8-k, roles of cur/nxt swapped ----
    float* outN = out;                                   // (6, B, T, H)
    float* outB = out + (size_t)Hc * NPc * Hc;           // (6, B, T)
    float* outL = outB + (size_t)Hc * NPc;               // (B, T)
#pragma unroll
    for (int k = 0; k < Hc; ++k) {
        const int n = (Gc - Hc) - k;   // 8 - k
#pragma unroll
        for (int i = 0; i < n - 1; ++i)
            gprod(nxt[i], nxt[i + 1], cur[i], cur[i + 1], bb[i], bb[i + 1], k);
        // kept_n[k] = nxt[n-1], kept_b[k] = bb[n-1]
        float2* od = reinterpret_cast<float2*>(outN + (size_t)k * NPc * Hc + (size_t)p * Hc);
        od[0] = make_float2(nxt[n - 1][0], nxt[n - 1][1]);
        od[1] = make_float2(nxt[n - 1][2], nxt[n - 1][3]);
        od[2] = make_float2(nxt[n - 1][4], nxt[n - 1][5]);
        outB[(size_t)k * NPc + p] = bb[n - 1];
    }

    // ---- epilogue: remaining biases (slots 0,1) ----
    LC += -0.5f * (LOG_2PI + bb[0] * bb[0]);
    LC += -0.5f * (LOG_2PI + bb[1] * bb[1]);
    outL[p] = LC;
}

extern "C" void kernel_launch(void* const* d_in, const int* in_sizes, int n_in,
                              void* d_out, int out_size, void* d_ws, size_t ws_size,
                              hipStream_t stream) {
    const float* cur = (const float*)d_in[0];
    const float* nxt = (const float*)d_in[1];
    const float* bia = (const float*)d_in[2];
    float* out = (float*)d_out;

    dim3 grid(NPc / 256), block(256);
    gaussmerge_kernel<<<grid, block, 0, stream>>>(cur, nxt, bia, out);
}